// Round 20
// baseline (81.893 us; speedup 1.0000x reference)
//
#include <hip/hip_runtime.h>
#include <stdint.h>

typedef short bf16x8 __attribute__((ext_vector_type(8)));
typedef __fp16 f16x2 __attribute__((ext_vector_type(2)));
typedef __fp16 f16x4 __attribute__((ext_vector_type(4)));
typedef float f32x4 __attribute__((ext_vector_type(4)));
typedef unsigned short u16;

static __device__ __forceinline__ f32x4 mfma_bf16_k32(bf16x8 a, bf16x8 b, f32x4 c) {
  return __builtin_amdgcn_mfma_f32_16x16x32_bf16(a, b, c, 0, 0, 0);
}
static __device__ __forceinline__ f32x4 mfma_f16_k16(f16x4 a, f16x4 b, f32x4 c) {
  return __builtin_amdgcn_mfma_f32_16x16x16f16(a, b, c, 0, 0, 0);
}

static __device__ __forceinline__ float fast_exp2(float x) {
#if __has_builtin(__builtin_amdgcn_exp2f)
  return __builtin_amdgcn_exp2f(x);   // raw v_exp_f32, no ocml fixup
#else
  return exp2f(x);
#endif
}

static __device__ __forceinline__ u16 f2bf(float f) {
  union { float f; uint32_t u; } v; v.f = f;
  uint32_t u = v.u;
  u += 0x7FFFu + ((u >> 16) & 1u);   // RNE
  return (u16)(u >> 16);
}

// XOR-swizzled LDS offset for [row][128B-row] tiles (T2/G4)
static __device__ __forceinline__ int lds_off(int row, int col) {
  return row * 128 + (col ^ ((row & 7) << 4));
}

// ---------------- kernel 0: W -> WTp, MFMA-fragment-packed bf16 -----------------
__global__ __launch_bounds__(256) void prep_wt(const float* __restrict__ Wk,
                                               const float* __restrict__ Wq,
                                               const float* __restrict__ Wv,
                                               u16* __restrict__ WTp) {
  int idx = blockIdx.x * 256 + threadIdx.x;   // 24576 threads, 8 elems each
  if (idx >= 24576) return;
  const int lane = idx & 63, kc = (idx >> 6) & 31, nt = idx >> 11;
  const int l15 = lane & 15, g = lane >> 4;
  int n = nt * 16 + l15;
  const int k0 = kc * 32 + 8 * g;
  const float* W;
  float scale = 1.0f;
  if (n < 64)        { W = Wq; scale = 0.125f * 1.44269504088896f; }
  else if (n < 128)  { W = Wk; n -= 64; }
  else               { W = Wv; n -= 128; }
  union { u16 s[8]; bf16x8 v; } cv;
#pragma unroll
  for (int j = 0; j < 8; ++j) cv.s[j] = f2bf(W[(k0 + j) * 64 + n] * scale);
  *(bf16x8*)(WTp + (size_t)idx * 8) = cv.v;
}

// ---------------- kernel 1: QKV projection, LDS-staged x, n-split ---------------
__global__ __launch_bounds__(256) void qkv_proj(const float* __restrict__ x,
                                                const u16* __restrict__ WTp,
                                                u16* __restrict__ Q,
                                                u16* __restrict__ K,
                                                __fp16* __restrict__ VT) {
  __shared__ __align__(16) char xs[32768];   // [16 rows][1024 bf16], swizzled 16B units
  const int lane = threadIdx.x & 63;
  const int wv   = threadIdx.x >> 6;
  const int l15  = lane & 15, g = lane >> 4;
  const long r0  = (long)blockIdx.x * 16;

  // ---- stage: wave wv loads rows 4wv..4wv+3, 1KB coalesced per instr ----
#pragma unroll
  for (int rr = 0; rr < 4; ++rr) {
    const int row = wv * 4 + rr;
    const float* xp = x + (r0 + row) * 1024;
#pragma unroll
    for (int ii = 0; ii < 4; ++ii) {
      float4 f = *(const float4*)(xp + ii * 256 + lane * 4);
      union { u16 s[4]; uint2 u; } cv;
      cv.s[0] = f2bf(f.x); cv.s[1] = f2bf(f.y);
      cv.s[2] = f2bf(f.z); cv.s[3] = f2bf(f.w);
      int off = row * 2048 + ii * 512 + lane * 8;
      off ^= (row & 7) << 4;                      // same involution as read side
      *(uint2*)&xs[off] = cv.u;
    }
  }
  __syncthreads();

  // ---- main: 32 kc-steps, 3 n-tiles per wave, A from LDS, B from packed WTp ----
  f32x4 acc[3];
#pragma unroll
  for (int j = 0; j < 3; ++j) acc[j] = (f32x4){0.f, 0.f, 0.f, 0.f};

  const u16* wbase = WTp + (size_t)(3 * wv) * 16384 + lane * 8;

#pragma unroll 8
  for (int kc = 0; kc < 32; ++kc) {
    int aoff = l15 * 2048 + kc * 64 + g * 16;
    aoff ^= (l15 & 7) << 4;
    bf16x8 af = *(const bf16x8*)&xs[aoff];
#pragma unroll
    for (int j = 0; j < 3; ++j) {
      bf16x8 bf = *(const bf16x8*)(wbase + (size_t)j * 16384 + kc * 512);
      acc[j] = mfma_bf16_k32(af, bf, acc[j]);
    }
  }

  // ---- epilogue ----
  const int b = (int)(r0 >> 12), sb = (int)(r0 & 4095);
#pragma unroll
  for (int j = 0; j < 3; ++j) {
    const int n = 3 * wv + j;
    f32x4 r = acc[j];
    if (n < 4) {
#pragma unroll
      for (int i = 0; i < 4; ++i)
        Q[(r0 + 4 * g + i) * 64 + n * 16 + l15] = f2bf(r[i]);
    } else if (n < 8) {
#pragma unroll
      for (int i = 0; i < 4; ++i)
        K[(r0 + 4 * g + i) * 64 + (n - 4) * 16 + l15] = f2bf(r[i]);
    } else {
      union { f16x2 h[2]; uint2 u; } vv;
      vv.h[0] = __builtin_amdgcn_cvt_pkrtz(r[0], r[1]);
      vv.h[1] = __builtin_amdgcn_cvt_pkrtz(r[2], r[3]);
      *(uint2*)(VT + (long)b * 262144 + ((n - 8) * 16 + l15) * 4096 + sb + 4 * g) = vv.u;
    }
  }
}

// ---------------- kernel 2: flash attention (8 waves x 16 q-rows) ---------------
// R12 shape (flash 47.4us, VGPR 44, clean traffic) + nspl=8: grid 1024 blocks of
// 512 threads -> 4 blocks/CU = 32 waves/CU = 8 waves/SIMD (was 4). Occupancy
// scales ONLY with nspl in this decomposition (q gives 1024 waves fixed); all
// prior nspl=8 attempts were confounded (VGPR caps / halved q-waves / spills).
// Chunk 0's po lives in d_out (saves 4MB ws so the nspl=8 tier can engage).
// 2-strip variants (R13-R18): compiler caps VGPR at 64 + spills -- do not revisit.
// p = exp2(s), no max shift; row sums ride the MFMA pipe (all-ones A fragment).
__global__ __launch_bounds__(512, 4) void flash_attn(const u16* __restrict__ Q,
                                                     const u16* __restrict__ K,
                                                     const __fp16* __restrict__ VT,
                                                     float* __restrict__ out,
                                                     float* __restrict__ po_ws,
                                                     float* __restrict__ pl,
                                                     int niter, int direct) {
  __shared__ __align__(16) char kv_lds[2][2][8192];   // [buf][K|V][64 rows x 128B]
  const int lane = threadIdx.x & 63, wv = threadIdx.x >> 6;   // wv 0..7
  const int l15 = lane & 15, g = lane >> 4;
  const int tile = (int)blockIdx.x & 127;
  const int c = (int)blockIdx.x >> 7;
  const int b = tile >> 5;
  const int r = (tile & 31) * 128 + wv * 16;
  const long qglob = (long)b * 4096 + r;
  const int t0 = c * niter;

  const char* Kb = (const char*)(K  + (long)b * 262144);
  const char* Vb = (const char*)(VT + (long)b * 262144);

  bf16x8 qf[2];
#pragma unroll
  for (int h = 0; h < 2; ++h)
    qf[h] = *(const bf16x8*)(Q + (qglob + l15) * 64 + 32 * h + 8 * g);

  f32x4 o[4];
#pragma unroll
  for (int n = 0; n < 4; ++n) o[n] = (f32x4){0.f, 0.f, 0.f, 0.f};
  f32x4 lacc = (f32x4){0.f, 0.f, 0.f, 0.f};
  const f32x4 zero4 = (f32x4){0.f, 0.f, 0.f, 0.f};
  const f16x4 one4 = {(__fp16)1.f, (__fp16)1.f, (__fp16)1.f, (__fp16)1.f};

  // staging: 16 chunks of 1KB (8 K + 8 V); wave wv owns chunks 2wv, 2wv+1
  uint4 sd[2];
  auto stage_load = [&](int t) {
#pragma unroll
    for (int jj = 0; jj < 2; ++jj) {
      const int j = wv * 2 + jj;
      const int d = (j & 7) * 1024 + lane * 16;
      const char* src;
      if (j < 8) src = Kb + (long)t * 8192 + d;
      else       src = Vb + (long)(d >> 7) * 8192 + (long)t * 128 + (d & 127);
      sd[jj] = *(const uint4*)src;
    }
  };
  auto stage_write = [&](int buf) {
#pragma unroll
    for (int jj = 0; jj < 2; ++jj) {
      const int j = wv * 2 + jj;
      const int d = (j & 7) * 1024 + lane * 16;
      const int off = d ^ (((d >> 7) & 7) << 4);
      *(uint4*)&kv_lds[buf][j < 8 ? 0 : 1][off] = sd[jj];
    }
  };

  // compute tile t from buffer cb; if stage: prefetch t+1 into cb^1
  auto body = [&](int cb, int t, bool stage) {
    if (stage) stage_load(t + 1);

    bf16x8 kf[4][2];
#pragma unroll
    for (int tt = 0; tt < 4; ++tt)
#pragma unroll
      for (int h = 0; h < 2; ++h)
        kf[tt][h] = *(const bf16x8*)&kv_lds[cb][0][lds_off(tt * 16 + l15, 64 * h + 16 * g)];
    f16x4 vf[4][4];
#pragma unroll
    for (int n = 0; n < 4; ++n)
#pragma unroll
      for (int tt = 0; tt < 4; ++tt)
        vf[n][tt] = *(const f16x4*)&kv_lds[cb][1][lds_off(16 * n + l15, 32 * tt + 8 * g)];

    f32x4 st[4];
#pragma unroll
    for (int tt = 0; tt < 4; ++tt) {
      st[tt] = mfma_bf16_k32(kf[tt][0], qf[0], zero4);
      st[tt] = mfma_bf16_k32(kf[tt][1], qf[1], st[tt]);
    }
#pragma unroll
    for (int tt = 0; tt < 4; ++tt)
#pragma unroll
      for (int i = 0; i < 4; ++i) st[tt][i] = fast_exp2(st[tt][i]);
    f16x4 pb[4];
#pragma unroll
    for (int tt = 0; tt < 4; ++tt) {
      union { f16x2 h[2]; f16x4 v; } u;
      u.h[0] = __builtin_amdgcn_cvt_pkrtz(st[tt][0], st[tt][1]);
      u.h[1] = __builtin_amdgcn_cvt_pkrtz(st[tt][2], st[tt][3]);
      pb[tt] = u.v;
    }

#pragma unroll
    for (int tt = 0; tt < 4; ++tt)
      lacc = mfma_f16_k16(one4, pb[tt], lacc);
#pragma unroll
    for (int tt = 0; tt < 4; ++tt)
#pragma unroll
      for (int n = 0; n < 4; ++n)
        o[n] = mfma_f16_k16(vf[n][tt], pb[tt], o[n]);

    if (stage) stage_write(cb ^ 1);
    __syncthreads();
  };

  stage_load(t0);
  stage_write(0);
  __syncthreads();

  for (int it = 0; it + 2 < niter; it += 2) {   // niter even (8/16/32/64)
    body(0, t0 + it, true);
    body(1, t0 + it + 1, true);
  }
  body(0, t0 + niter - 2, true);
  body(1, t0 + niter - 1, false);

  const float lsum = lacc[0];   // replicated rows of ones.P
  if (direct) {
    float linv = 1.f / lsum;
#pragma unroll
    for (int n = 0; n < 4; ++n) {
      float4 v = {o[n][0] * linv, o[n][1] * linv, o[n][2] * linv, o[n][3] * linv};
      *(float4*)(out + (qglob + l15) * 64 + n * 16 + 4 * g) = v;
    }
  } else {
    // chunk 0's partials live in d_out; chunks 1.. in workspace
    float* pob = (c == 0) ? out : po_ws + (size_t)(c - 1) * (16384 * 64);
    const long pr = qglob + l15;
#pragma unroll
    for (int n = 0; n < 4; ++n) {
      float4 v = {o[n][0], o[n][1], o[n][2], o[n][3]};
      *(float4*)(pob + pr * 64 + n * 16 + 4 * g) = v;   // full-line stores
    }
    if (g == 0) pl[c * 16384 + pr] = lsum;
  }
}

// ---------------- kernel 3: combine KV-split partials (common scale) ------------
// Chunk 0 partials are read from `out` and then overwritten (same-thread
// read-before-write on the same address -- race-free).
__global__ __launch_bounds__(256) void combine(const float* __restrict__ po_ws,
                                               const float* __restrict__ pl,
                                               float* __restrict__ out, int nspl) {
  const int r = blockIdx.x * 4 + (threadIdx.x >> 6);
  const int h = threadIdx.x & 63;
  float L = pl[r], acc = out[(long)r * 64 + h];   // chunk 0 from out
  for (int c = 1; c < nspl; ++c) {
    L += pl[c * 16384 + r];
    acc += po_ws[((long)(c - 1) * 16384 + r) * 64 + h];
  }
  out[(long)r * 64 + h] = acc / L;
}

// ---------------- launch --------------------------------------------------------
extern "C" void kernel_launch(void* const* d_in, const int* in_sizes, int n_in,
                              void* d_out, int out_size, void* d_ws, size_t ws_size,
                              hipStream_t stream) {
  const float* x  = (const float*)d_in[0];
  const float* Wk = (const float*)d_in[1];
  const float* Wq = (const float*)d_in[2];
  const float* Wv = (const float*)d_in[3];
  float* out = (float*)d_out;

  char* ws = (char*)d_ws;
  u16* WTp    = (u16*)ws;                               // 384 KiB (fragment-packed)
  u16* Q      = (u16*)(ws + 393216);                    // 2 MiB
  u16* K      = (u16*)(ws + 393216 + 2097152);          // 2 MiB
  __fp16* VT  = (__fp16*)(ws + 393216 + 2 * 2097152);   // 2 MiB (f16)
  const size_t base = 393216 + 3 * 2097152;             // 6684672
  const size_t poc  = (size_t)16384 * 64 * 4;           // 4 MiB per po chunk
  const size_t plsz = (size_t)16384 * 4;                // 64 KiB per pl chunk

  // chunk 0's po lives in d_out -> ws holds (nspl-1) po chunks + nspl pl chunks
  int nspl, direct;
  if (ws_size >= base + 7 * poc + 8 * plsz)      { nspl = 8; direct = 0; }
  else if (ws_size >= base + 3 * poc + 4 * plsz) { nspl = 4; direct = 0; }
  else if (ws_size >= base + 1 * poc + 2 * plsz) { nspl = 2; direct = 0; }
  else                                           { nspl = 1; direct = 1; }

  float* po_ws = (float*)(ws + base);
  float* pl    = po_ws + (size_t)(nspl - 1) * 16384 * 64;

  prep_wt<<<96, 256, 0, stream>>>(Wk, Wq, Wv, WTp);
  qkv_proj<<<1024, 256, 0, stream>>>(x, WTp, Q, K, VT);
  flash_attn<<<128 * nspl, 512, 0, stream>>>(Q, K, VT, out, po_ws, pl, 64 / nspl, direct);
  if (!direct) combine<<<4096, 256, 0, stream>>>(po_ws, pl, out, nspl);
}